// Round 13
// baseline (140.621 us; speedup 1.0000x reference)
//
#include <hip/hip_runtime.h>
#include <stdint.h>

typedef __attribute__((ext_vector_type(8))) short short8;
typedef __attribute__((ext_vector_type(4))) float f32x4;
typedef __attribute__((ext_vector_type(4))) unsigned short ushort4v;
typedef __attribute__((ext_vector_type(2))) unsigned int uint2v;

static __device__ __forceinline__ unsigned short f2b(float f) {
  union { float f; unsigned int u; } v; v.f = f;
  unsigned int r = v.u + 0x7FFFu + ((v.u >> 16) & 1u);
  return (unsigned short)(r >> 16);
}

static __device__ __forceinline__ float exp2fast(float x) {
#if __has_builtin(__builtin_amdgcn_exp2f)
  return __builtin_amdgcn_exp2f(x);
#else
  return exp2f(x);
#endif
}

static __device__ __forceinline__ unsigned int cvtpk(float lo, float hi) {
  unsigned int r;
  asm("v_cvt_pk_bf16_f32 %0, %1, %2" : "=v"(r) : "v"(lo), "v"(hi));
  return r;
}

// Cross-lane ^16 / ^32 reduces via permlane*_swap (VALU) - verified r5/r6.
static __device__ __forceinline__ float xor16max(float x) {
#if __has_builtin(__builtin_amdgcn_permlane16_swap)
  unsigned u = __float_as_uint(x);
  uint2v r = __builtin_amdgcn_permlane16_swap(u, u, false, false);
  return fmaxf(__uint_as_float(r[0]), __uint_as_float(r[1]));
#else
  return fmaxf(x, __shfl_xor(x, 16));
#endif
}
static __device__ __forceinline__ float xor32max(float x) {
#if __has_builtin(__builtin_amdgcn_permlane32_swap)
  unsigned u = __float_as_uint(x);
  uint2v r = __builtin_amdgcn_permlane32_swap(u, u, false, false);
  return fmaxf(__uint_as_float(r[0]), __uint_as_float(r[1]));
#else
  return fmaxf(x, __shfl_xor(x, 32));
#endif
}
static __device__ __forceinline__ float xor16add(float x) {
#if __has_builtin(__builtin_amdgcn_permlane16_swap)
  unsigned u = __float_as_uint(x);
  uint2v r = __builtin_amdgcn_permlane16_swap(u, u, false, false);
  return __uint_as_float(r[0]) + __uint_as_float(r[1]);
#else
  return x + __shfl_xor(x, 16);
#endif
}
static __device__ __forceinline__ float xor32add(float x) {
#if __has_builtin(__builtin_amdgcn_permlane32_swap)
  unsigned u = __float_as_uint(x);
  uint2v r = __builtin_amdgcn_permlane32_swap(u, u, false, false);
  return __uint_as_float(r[0]) + __uint_as_float(r[1]);
#else
  return x + __shfl_xor(x, 32);
#endif
}

static __device__ __forceinline__ void gload16(const void* g, void* l) {
  __builtin_amdgcn_global_load_lds(
      (const __attribute__((address_space(1))) unsigned int*)g,
      (__attribute__((address_space(3))) unsigned int*)l, 16, 0, 0);
}

// ---------------- fused prep: cast_x | weight transpose | rope tables ----------------

__global__ __launch_bounds__(256) void prep_kernel(
    const float* __restrict__ x, const float* __restrict__ wq,
    const float* __restrict__ wk, const float* __restrict__ wv,
    const float* __restrict__ wo, unsigned short* __restrict__ xb,
    unsigned short* __restrict__ wT, float* __restrict__ ct,
    float* __restrict__ st) {
  __shared__ float t[32][33];
  const int bid = blockIdx.x, tid = threadIdx.x;
  if (bid < 4096) {  // cast x -> bf16
    int i = (bid * 256 + tid) * 4;
    float4 v = *(const float4*)(x + i);
    ushort4v o = { f2b(v.x), f2b(v.y), f2b(v.z), f2b(v.w) };
    *(ushort4v*)(xb + i) = o;
  } else if (bid < 8192) {  // transpose+cast weights
    int tt = bid - 4096;
    int z = tt >> 10, xy = tt & 1023;
    const float* src = (z == 0) ? wq : (z == 1) ? wk : (z == 2) ? wv : wo;
    unsigned short* dst = wT + (size_t)z * 1048576;
    int tx = tid & 31, ty = tid >> 5;
    int n0 = (xy & 31) * 32, k0 = (xy >> 5) * 32;
#pragma unroll
    for (int i = 0; i < 4; ++i) {
      int r = ty + i * 8;
      t[r][tx] = src[(size_t)(k0 + r) * 1024 + n0 + tx];
    }
    __syncthreads();
#pragma unroll
    for (int i = 0; i < 4; ++i) {
      int r = ty + i * 8;
      dst[(size_t)(n0 + r) * 1024 + k0 + tx] = f2b(t[tx][r]);
    }
  } else {  // rope tables (2048*32 entries)
    int i = (bid - 8192) * 256 + tid;
    int s = i >> 5, p = i & 31;
    float ang = (float)s * powf(10000.0f, -(float)(2 * p) / 64.0f);
    ct[i] = cosf(ang);
    st[i] = sinf(ang);
  }
}

// ---------------- QKV GEMM: 128x128 tile, K-step 64 via two BK=32 LDS panels --------

__global__ __launch_bounds__(256) void gemm_kernel(
    const unsigned short* __restrict__ A, const unsigned short* __restrict__ WT,
    unsigned short* __restrict__ Qb, unsigned short* __restrict__ Kb,
    unsigned short* __restrict__ VTb,
    const float* __restrict__ ctab, const float* __restrict__ stab) {
  __shared__ unsigned short As[2][128 * 32];
  __shared__ unsigned short Bs[2][128 * 32];
  const int tid = threadIdx.x;
  const int w = tid >> 6, lane = tid & 63;
  const int m0 = blockIdx.x * 128, n0 = blockIdx.y * 128;
  const int mode = blockIdx.z;
  const unsigned short* Bt = WT + (size_t)mode * 1048576;
  const int wr = w >> 1, wc = w & 1;
  const int srow = lane >> 2, scol = lane & 3;
  f32x4 acc[4][4] = {};
  for (int k0 = 0; k0 < 1024; k0 += 64) {
#pragma unroll
    for (int p = 0; p < 2; ++p)
#pragma unroll
      for (int c = 0; c < 2; ++c) {
        int chunk = w * 2 + c;
        gload16(A + (size_t)(m0 + chunk * 16 + srow) * 1024 + k0 + p * 32 + scol * 8,
                (char*)As[p] + chunk * 1024);
        gload16(Bt + (size_t)(n0 + chunk * 16 + srow) * 1024 + k0 + p * 32 + scol * 8,
                (char*)Bs[p] + chunk * 1024);
      }
    __syncthreads();
#pragma unroll
    for (int p = 0; p < 2; ++p) {
      short8 af[4], bf[4];
#pragma unroll
      for (int i = 0; i < 4; ++i) {
        af[i] = *(const short8*)((const char*)As[p] +
                ((wr * 64 + i * 16 + (lane & 15)) * 64 + (lane >> 4) * 16));
        bf[i] = *(const short8*)((const char*)Bs[p] +
                ((wc * 64 + i * 16 + (lane & 15)) * 64 + (lane >> 4) * 16));
      }
#pragma unroll
      for (int i = 0; i < 4; ++i)
#pragma unroll
        for (int j = 0; j < 4; ++j)
          acc[i][j] = __builtin_amdgcn_mfma_f32_16x16x32_bf16(af[i], bf[j], acc[i][j], 0, 0, 0);
    }
    __syncthreads();
  }

  if (mode < 2) {
    unsigned short* dst = mode ? Kb : Qb;
    const float qscale = mode ? 1.0f : 0.125f * 1.44269504088896f;
#pragma unroll
    for (int i = 0; i < 4; ++i) {
#pragma unroll
      for (int j = 0; j < 4; ++j) {
        int n = n0 + wc * 64 + j * 16 + (lane & 15);
        int h = n >> 6, d = n & 63;
        int pairIdx = d >> 1;
        bool even = (n & 1) == 0;
#pragma unroll
        for (int r = 0; r < 4; ++r) {
          int m = m0 + wr * 64 + i * 16 + (lane >> 4) * 4 + r;
          int b = m >> 11, s = m & 2047;
          float v = acc[i][j][r];
          float pv = __shfl_xor(v, 1);
          float c = ctab[s * 32 + pairIdx], sn = stab[s * 32 + pairIdx];
          float ov = (even ? (v * c - pv * sn) : (pv * sn + v * c)) * qscale;
          dst[(size_t)((h * 2 + b) * 2048 + s) * 64 + d] = f2b(ov);
        }
      }
    }
  } else {
#pragma unroll
    for (int i = 0; i < 4; ++i) {
#pragma unroll
      for (int j = 0; j < 4; ++j) {
        int n = n0 + wc * 64 + j * 16 + (lane & 15);
        int h = n >> 6, d = n & 63;
        int mBase = m0 + wr * 64 + i * 16 + (lane >> 4) * 4;
        int b = mBase >> 11, s = mBase & 2047;
        ushort4v pk = { f2b(acc[i][j][0]), f2b(acc[i][j][1]),
                        f2b(acc[i][j][2]), f2b(acc[i][j][3]) };
        *(ushort4v*)(VTb + (size_t)((h * 2 + b) * 64 + d) * 2048 + s) = pk;
      }
    }
  }
}

// ---------------- final GEMM: 64x128 tile, 2-wave blocks, fp32 out ----------------

__global__ __launch_bounds__(128) void gemm_final_kernel(
    const unsigned short* __restrict__ A, const unsigned short* __restrict__ Bt,
    float* __restrict__ Fout) {
  __shared__ unsigned short As[64 * 32];
  __shared__ unsigned short Bs[128 * 32];
  const int tid = threadIdx.x;
  const int w = tid >> 6, lane = tid & 63;
  const int m0 = blockIdx.x * 64, n0 = blockIdx.y * 128;
  const int srow = lane >> 2, scol = lane & 3;
  f32x4 acc[4][4] = {};
  for (int k0 = 0; k0 < 1024; k0 += 32) {
#pragma unroll
    for (int c = 0; c < 2; ++c) {
      int chunk = w * 2 + c;
      gload16(A + (size_t)(m0 + chunk * 16 + srow) * 1024 + k0 + scol * 8,
              (char*)As + chunk * 1024);
    }
#pragma unroll
    for (int c = 0; c < 4; ++c) {
      int chunk = w * 4 + c;
      gload16(Bt + (size_t)(n0 + chunk * 16 + srow) * 1024 + k0 + scol * 8,
              (char*)Bs + chunk * 1024);
    }
    __syncthreads();
    short8 af[4], bf[4];
#pragma unroll
    for (int i = 0; i < 4; ++i) {
      af[i] = *(const short8*)((const char*)As +
              ((i * 16 + (lane & 15)) * 64 + (lane >> 4) * 16));
      bf[i] = *(const short8*)((const char*)Bs +
              ((w * 64 + i * 16 + (lane & 15)) * 64 + (lane >> 4) * 16));
    }
#pragma unroll
    for (int i = 0; i < 4; ++i)
#pragma unroll
      for (int j = 0; j < 4; ++j)
        acc[i][j] = __builtin_amdgcn_mfma_f32_16x16x32_bf16(af[i], bf[j], acc[i][j], 0, 0, 0);
    __syncthreads();
  }
#pragma unroll
  for (int i = 0; i < 4; ++i)
#pragma unroll
    for (int j = 0; j < 4; ++j) {
      int n = n0 + w * 64 + j * 16 + (lane & 15);
#pragma unroll
      for (int r = 0; r < 4; ++r) {
        int m = m0 + i * 16 + (lane >> 4) * 4 + r;
        Fout[(size_t)m * 1024 + n] = acc[i][j][r];
      }
    }
}

// ---------------- causal flash attention: pair + parity k-split ----------------
// Job = (pair p, hb, parity). Block runs r6's exact inner loop for qtL=p and
// qtH=31-p but only kt == parity (mod 2). Work = 17 (parity0) / 16 (parity1)
// units for EVERY job -> 1024 equal blocks = 4/CU supply (LDS capacity 4/CU).
// Emits unnormalized partials (bf16 O + row m/ls); combine merges parities.

__device__ __forceinline__ void proc_tile(
    const short8 aq[2], const unsigned short* Ksb, const unsigned short* Vsb,
    char* Psw, int lq, int lh, int wq16, bool diag,
    float& m, float& ls, f32x4* o) {
  const int swq = (lq & 7) << 4;
  f32x4 sacc[4] = {};
  __builtin_amdgcn_s_setprio(1);
#pragma unroll
  for (int ct = 0; ct < 4; ++ct) {
    const char* base = (const char*)Ksb + (ct * 16 + lq) * 128;
#pragma unroll
    for (int half = 0; half < 2; ++half) {
      short8 ak = *(const short8*)(base + ((half * 64 + lh * 16) ^ swq));
      sacc[ct] = __builtin_amdgcn_mfma_f32_16x16x32_bf16(ak, aq[half], sacc[ct], 0, 0, 0);
    }
  }
  __builtin_amdgcn_s_setprio(0);

  if (diag) {  // mask if k_local = 16ct + 4lh + r > q_local = wq16 + lq
    int rel = wq16 + lq - 4 * lh;
#pragma unroll
    for (int ct = 0; ct < 4; ++ct)
#pragma unroll
      for (int r = 0; r < 4; ++r)
        if (ct * 16 + r > rel) sacc[ct][r] = -__builtin_inff();
  }

  float mx0 = fmaxf(fmaxf(sacc[0][0], sacc[0][1]), fmaxf(sacc[0][2], sacc[0][3]));
  float mx1 = fmaxf(fmaxf(sacc[1][0], sacc[1][1]), fmaxf(sacc[1][2], sacc[1][3]));
  float mx2 = fmaxf(fmaxf(sacc[2][0], sacc[2][1]), fmaxf(sacc[2][2], sacc[2][3]));
  float mx3 = fmaxf(fmaxf(sacc[3][0], sacc[3][1]), fmaxf(sacc[3][2], sacc[3][3]));
  float mx = fmaxf(fmaxf(mx0, mx1), fmaxf(mx2, mx3));
  mx = xor16max(mx);
  mx = xor32max(mx);
  float nm = fmaxf(m, mx);
  float al = exp2fast(m - nm);
  m = nm;
  float ps = 0.f;
#pragma unroll
  for (int ct = 0; ct < 4; ++ct)
#pragma unroll
    for (int r = 0; r < 4; ++r) {
      float p = exp2fast(sacc[ct][r] - nm);
      sacc[ct][r] = p;
      ps += p;
    }
  ls = ls * al + ps;  // per-lane partial; cross-lane reduce deferred to epilogue
#pragma unroll
  for (int ct = 0; ct < 4; ++ct)
#pragma unroll
    for (int r = 0; r < 4; ++r) o[ct][r] *= al;

  // P[q=lq][k=16ct+4lh+{0..3}] -> one b64 write per ct (4 contiguous k)
#pragma unroll
  for (int ct = 0; ct < 4; ++ct) {
    uint2v pk = { cvtpk(sacc[ct][0], sacc[ct][1]), cvtpk(sacc[ct][2], sacc[ct][3]) };
    *(uint2v*)(Psw + lq * 128 + ((ct * 32 + lh * 8) ^ swq)) = pk;
  }
  __builtin_amdgcn_wave_barrier();
  short8 pa[2];
#pragma unroll
  for (int half = 0; half < 2; ++half)
    pa[half] = *(const short8*)(Psw + lq * 128 + ((half * 64 + lh * 16) ^ swq));

  __builtin_amdgcn_s_setprio(1);
#pragma unroll
  for (int ct = 0; ct < 4; ++ct) {
    const char* base = (const char*)Vsb + (ct * 16 + lq) * 128;
#pragma unroll
    for (int half = 0; half < 2; ++half) {
      short8 av = *(const short8*)(base + ((half * 64 + lh * 16) ^ swq));
      o[ct] = __builtin_amdgcn_mfma_f32_16x16x32_bf16(av, pa[half], o[ct], 0, 0, 0);
    }
  }
  __builtin_amdgcn_s_setprio(0);
}

__device__ __forceinline__ void store_partial(
    const f32x4* o, float m, float ls, char* Psw,
    unsigned short* __restrict__ P, float* __restrict__ mlsT,
    int lane, int lq, int lh, int w) {
  float l = xor32add(xor16add(ls));  // deferred l reduction
  if (lh == 0) {                      // one lane per q-row
    mlsT[w * 16 + lq] = m;
    mlsT[64 + w * 16 + lq] = l;
  }
#pragma unroll
  for (int ct = 0; ct < 4; ++ct)
#pragma unroll
    for (int r = 0; r < 4; ++r) {
      int d = ct * 16 + lh * 4 + r;
      *(unsigned short*)(Psw + lq * 128 + ((2 * d) ^ ((lq & 7) << 4))) = f2b(o[ct][r]);
    }
  __builtin_amdgcn_wave_barrier();  // Psw is wave-private
#pragma unroll
  for (int pass = 0; pass < 2; ++pass) {
    int q2 = pass * 8 + (lane >> 3), d0 = (lane & 7) * 8;
    short8 vrow = *(const short8*)(Psw + q2 * 128 + ((2 * d0) ^ ((q2 & 7) << 4)));
    *(short8*)(P + (size_t)(w * 16 + q2) * 64 + d0) = vrow;
  }
  __builtin_amdgcn_wave_barrier();
}

__global__ __launch_bounds__(256) void attn_kernel(
    const unsigned short* __restrict__ Qb, const unsigned short* __restrict__ Kb,
    const unsigned short* __restrict__ VTb, unsigned short* __restrict__ P0,
    unsigned short* __restrict__ P1, float* __restrict__ mls) {
  __shared__ unsigned short Ks[2][64 * 64];
  __shared__ unsigned short Vs[2][64 * 64];
  __shared__ unsigned short Ps[4 * 16 * 64];
  const int tid = threadIdx.x, w = tid >> 6, lane = tid & 63;
  const int parity = blockIdx.x >> 4, pi = blockIdx.x & 15;
  const int qtL = pi, qtH = 31 - pi;
  const int hb = blockIdx.y;
  const unsigned short* Qhb = Qb + (size_t)hb * 2048 * 64;
  const unsigned short* Khb = Kb + (size_t)hb * 2048 * 64;
  const unsigned short* Vhb = VTb + (size_t)hb * 64 * 2048;
  char* Psw = (char*)Ps + w * 2048;
  const int lq = lane & 15, lh = lane >> 4;
  const int wq16 = w * 16;

  short8 aqL[2], aqH[2];
  {
    int rowL = qtL * 64 + wq16 + lq;
    int rowH = qtH * 64 + wq16 + lq;
#pragma unroll
    for (int half = 0; half < 2; ++half) {
      aqL[half] = *(const short8*)(Qhb + (size_t)rowL * 64 + half * 32 + lh * 8);
      aqH[half] = *(const short8*)(Qhb + (size_t)rowH * 64 + half * 32 + lh * 8);
    }
  }
  float mL = -__builtin_inff(), lsL = 0.f;
  float mH = -__builtin_inff(), lsH = 0.f;
  f32x4 oL[4] = {}, oH[4] = {};

  // staging: thread owns rows r0, r0+32 (16B each)
  const int r0 = tid >> 3, f0 = tid & 7;
  const int so0 = r0 * 128 + ((f0 * 16) ^ ((r0 & 7) << 4));
  short8 gK[2], gV[2];
  {
    int kk0 = parity * 64;
    gK[0] = *(const short8*)(Khb + (size_t)(kk0 + r0) * 64 + f0 * 8);
    gK[1] = *(const short8*)(Khb + (size_t)(kk0 + r0 + 32) * 64 + f0 * 8);
    gV[0] = *(const short8*)(Vhb + (size_t)r0 * 2048 + kk0 + f0 * 8);
    gV[1] = *(const short8*)(Vhb + (size_t)(r0 + 32) * 2048 + kk0 + f0 * 8);
  }
  *(short8*)((char*)Ks[0] + so0) = gK[0];
  *(short8*)((char*)Ks[0] + so0 + 32 * 128) = gK[1];
  *(short8*)((char*)Vs[0] + so0) = gV[0];
  *(short8*)((char*)Vs[0] + so0 + 32 * 128) = gV[1];
  __syncthreads();

  int buf = 0;
  for (int kt = parity; kt <= qtH; kt += 2) {
    const bool pf = (kt + 2 <= qtH);
    if (pf) {  // issue tile kt+2's loads; latency hides under compute
      int kk0 = (kt + 2) * 64;
      gK[0] = *(const short8*)(Khb + (size_t)(kk0 + r0) * 64 + f0 * 8);
      gK[1] = *(const short8*)(Khb + (size_t)(kk0 + r0 + 32) * 64 + f0 * 8);
      gV[0] = *(const short8*)(Vhb + (size_t)r0 * 2048 + kk0 + f0 * 8);
      gV[1] = *(const short8*)(Vhb + (size_t)(r0 + 32) * 2048 + kk0 + f0 * 8);
    }
    proc_tile(aqH, Ks[buf], Vs[buf], Psw, lq, lh, wq16, kt == qtH, mH, lsH, oH);
    if (kt <= qtL)
      proc_tile(aqL, Ks[buf], Vs[buf], Psw, lq, lh, wq16, kt == qtL, mL, lsL, oL);
    if (pf) {
      *(short8*)((char*)Ks[buf ^ 1] + so0) = gK[0];
      *(short8*)((char*)Ks[buf ^ 1] + so0 + 32 * 128) = gK[1];
      *(short8*)((char*)Vs[buf ^ 1] + so0) = gV[0];
      *(short8*)((char*)Vs[buf ^ 1] + so0 + 32 * 128) = gV[1];
    }
    __syncthreads();
    buf ^= 1;
  }

  unsigned short* PP = parity ? P1 : P0;
  float* mlsP = mls + ((size_t)(parity * 32 + hb) * 32) * 128;
  store_partial(oL, mL, lsL, Psw, PP + (size_t)(hb * 32 + qtL) * 4096,
                mlsP + (size_t)qtL * 128, lane, lq, lh, w);
  store_partial(oH, mH, lsH, Psw, PP + (size_t)(hb * 32 + qtH) * 4096,
                mlsP + (size_t)qtH * 128, lane, lq, lh, w);
}

// ---------------- combine: merge the two parity partials ----------------

__global__ __launch_bounds__(256) void combine_kernel(
    const unsigned short* __restrict__ P0, const unsigned short* __restrict__ P1,
    const float* __restrict__ mls, unsigned short* __restrict__ Obf) {
  const int qt = blockIdx.x, hb = blockIdx.y, t = threadIdx.x;
  const int q = t >> 2, c0 = (t & 3) * 16;
  const float* m0p = mls + ((size_t)(0 * 32 + hb) * 32 + qt) * 128;
  const float* m1p = mls + ((size_t)(1 * 32 + hb) * 32 + qt) * 128;
  float m0 = m0p[q], ls0 = m0p[64 + q];
  float m1 = m1p[q], ls1 = m1p[64 + q];
  float M = fmaxf(m0, m1);
  float w0 = exp2fast(m0 - M), w1 = exp2fast(m1 - M);
  float inv = 1.0f / (ls0 * w0 + ls1 * w1);
  float f0 = w0 * inv, f1 = w1 * inv;
  size_t base = ((size_t)(hb * 32 + qt) * 64 + q) * 64 + c0;
  int b = hb & 1, h = hb >> 1;
  unsigned short* dst = Obf + ((size_t)(b * 2048 + qt * 64 + q)) * 1024 + h * 64 + c0;
#pragma unroll
  for (int c = 0; c < 16; c += 8) {
    union { short8 s; unsigned short u[8]; } a, bb, o;
    a.s = *(const short8*)(P0 + base + c);
    bb.s = *(const short8*)(P1 + base + c);
#pragma unroll
    for (int e = 0; e < 8; ++e) {
      float p0 = __uint_as_float((unsigned)a.u[e] << 16);
      float p1 = __uint_as_float((unsigned)bb.u[e] << 16);
      o.u[e] = f2b(p0 * f0 + p1 * f1);
    }
    *(short8*)(dst + c) = o.s;
  }
}

// ---------------- launch ----------------

extern "C" void kernel_launch(void* const* d_in, const int* in_sizes, int n_in,
                              void* d_out, int out_size, void* d_ws, size_t ws_size,
                              hipStream_t stream) {
  const float* x  = (const float*)d_in[0];
  const float* wq = (const float*)d_in[1];
  const float* wk = (const float*)d_in[2];
  const float* wv = (const float*)d_in[3];
  const float* wo = (const float*)d_in[4];
  float* out = (float*)d_out;

  char* ws = (char*)d_ws;
  const size_t SZ = 8388608;  // 8 MiB
  unsigned short* xb  = (unsigned short*)(ws);            // x bf16; later: P1 partials
  unsigned short* wT  = (unsigned short*)(ws + SZ);       // 4 x 2MiB (q,k,v,o)
  unsigned short* Qb  = (unsigned short*)(ws + 2 * SZ);   // Q; later: combined O (Obf)
  unsigned short* Kb  = (unsigned short*)(ws + 3 * SZ);
  unsigned short* VTb = (unsigned short*)(ws + 4 * SZ);
  unsigned short* P0  = (unsigned short*)(ws + 5 * SZ);   // parity-0 partials (8 MB)
  float* ctab = (float*)(ws + 6 * SZ);                    // rope tables; later: mls
  float* stab = ctab + 65536;
  float* mls  = ctab;                                     // 1 MB overlay on dead tables
  if (ws_size < 6 * SZ + 1048576) return;  // ws too small: fail loudly (zeros)

  unsigned short* P1  = xb;
  unsigned short* Obf = Qb;

  prep_kernel<<<8448, 256, 0, stream>>>(x, wq, wk, wv, wo, xb, wT, ctab, stab);
  gemm_kernel<<<dim3(32, 8, 3), 256, 0, stream>>>(xb, wT, Qb, Kb, VTb, ctab, stab);
  attn_kernel<<<dim3(32, 32), 256, 0, stream>>>(Qb, Kb, VTb, P0, P1, mls);
  combine_kernel<<<dim3(32, 32), 256, 0, stream>>>(P0, P1, mls, Obf);
  gemm_final_kernel<<<dim3(64, 8), 128, 0, stream>>>(Obf, wT + 3 * 1048576, out);
}

// Round 14
// 133.629 us; speedup vs baseline: 1.0523x; 1.0523x over previous
//
#include <hip/hip_runtime.h>
#include <stdint.h>

typedef __attribute__((ext_vector_type(8))) short short8;
typedef __attribute__((ext_vector_type(4))) float f32x4;
typedef __attribute__((ext_vector_type(4))) unsigned short ushort4v;
typedef __attribute__((ext_vector_type(2))) unsigned int uint2v;

static __device__ __forceinline__ unsigned short f2b(float f) {
  union { float f; unsigned int u; } v; v.f = f;
  unsigned int r = v.u + 0x7FFFu + ((v.u >> 16) & 1u);
  return (unsigned short)(r >> 16);
}

static __device__ __forceinline__ float exp2fast(float x) {
#if __has_builtin(__builtin_amdgcn_exp2f)
  return __builtin_amdgcn_exp2f(x);
#else
  return exp2f(x);
#endif
}

static __device__ __forceinline__ unsigned int cvtpk(float lo, float hi) {
  unsigned int r;
  asm("v_cvt_pk_bf16_f32 %0, %1, %2" : "=v"(r) : "v"(lo), "v"(hi));
  return r;
}

// Cross-lane ^16 / ^32 reduces via permlane*_swap (VALU) - verified r5/r6.
static __device__ __forceinline__ float xor16max(float x) {
#if __has_builtin(__builtin_amdgcn_permlane16_swap)
  unsigned u = __float_as_uint(x);
  uint2v r = __builtin_amdgcn_permlane16_swap(u, u, false, false);
  return fmaxf(__uint_as_float(r[0]), __uint_as_float(r[1]));
#else
  return fmaxf(x, __shfl_xor(x, 16));
#endif
}
static __device__ __forceinline__ float xor32max(float x) {
#if __has_builtin(__builtin_amdgcn_permlane32_swap)
  unsigned u = __float_as_uint(x);
  uint2v r = __builtin_amdgcn_permlane32_swap(u, u, false, false);
  return fmaxf(__uint_as_float(r[0]), __uint_as_float(r[1]));
#else
  return fmaxf(x, __shfl_xor(x, 32));
#endif
}
static __device__ __forceinline__ float xor16add(float x) {
#if __has_builtin(__builtin_amdgcn_permlane16_swap)
  unsigned u = __float_as_uint(x);
  uint2v r = __builtin_amdgcn_permlane16_swap(u, u, false, false);
  return __uint_as_float(r[0]) + __uint_as_float(r[1]);
#else
  return x + __shfl_xor(x, 16);
#endif
}
static __device__ __forceinline__ float xor32add(float x) {
#if __has_builtin(__builtin_amdgcn_permlane32_swap)
  unsigned u = __float_as_uint(x);
  uint2v r = __builtin_amdgcn_permlane32_swap(u, u, false, false);
  return __uint_as_float(r[0]) + __uint_as_float(r[1]);
#else
  return x + __shfl_xor(x, 32);
#endif
}

static __device__ __forceinline__ void gload16(const void* g, void* l) {
  __builtin_amdgcn_global_load_lds(
      (const __attribute__((address_space(1))) unsigned int*)g,
      (__attribute__((address_space(3))) unsigned int*)l, 16, 0, 0);
}

// ---------------- fused prep: cast_x | weight transpose | rope tables ----------------

__global__ __launch_bounds__(256) void prep_kernel(
    const float* __restrict__ x, const float* __restrict__ wq,
    const float* __restrict__ wk, const float* __restrict__ wv,
    const float* __restrict__ wo, unsigned short* __restrict__ xb,
    unsigned short* __restrict__ wT, float* __restrict__ ct,
    float* __restrict__ st) {
  __shared__ float t[32][33];
  const int bid = blockIdx.x, tid = threadIdx.x;
  if (bid < 4096) {  // cast x -> bf16
    int i = (bid * 256 + tid) * 4;
    float4 v = *(const float4*)(x + i);
    ushort4v o = { f2b(v.x), f2b(v.y), f2b(v.z), f2b(v.w) };
    *(ushort4v*)(xb + i) = o;
  } else if (bid < 8192) {  // transpose+cast weights
    int tt = bid - 4096;
    int z = tt >> 10, xy = tt & 1023;
    const float* src = (z == 0) ? wq : (z == 1) ? wk : (z == 2) ? wv : wo;
    unsigned short* dst = wT + (size_t)z * 1048576;
    int tx = tid & 31, ty = tid >> 5;
    int n0 = (xy & 31) * 32, k0 = (xy >> 5) * 32;
#pragma unroll
    for (int i = 0; i < 4; ++i) {
      int r = ty + i * 8;
      t[r][tx] = src[(size_t)(k0 + r) * 1024 + n0 + tx];
    }
    __syncthreads();
#pragma unroll
    for (int i = 0; i < 4; ++i) {
      int r = ty + i * 8;
      dst[(size_t)(n0 + r) * 1024 + k0 + tx] = f2b(t[tx][r]);
    }
  } else {  // rope tables (2048*32 entries)
    int i = (bid - 8192) * 256 + tid;
    int s = i >> 5, p = i & 31;
    float ang = (float)s * powf(10000.0f, -(float)(2 * p) / 64.0f);
    ct[i] = cosf(ang);
    st[i] = sinf(ang);
  }
}

// ---------------- QKV GEMM: 128x128 tile, K-step 64 via two BK=32 LDS panels --------

__global__ __launch_bounds__(256) void gemm_kernel(
    const unsigned short* __restrict__ A, const unsigned short* __restrict__ WT,
    unsigned short* __restrict__ Qb, unsigned short* __restrict__ Kb,
    unsigned short* __restrict__ VTb,
    const float* __restrict__ ctab, const float* __restrict__ stab) {
  __shared__ unsigned short As[2][128 * 32];
  __shared__ unsigned short Bs[2][128 * 32];
  const int tid = threadIdx.x;
  const int w = tid >> 6, lane = tid & 63;
  const int m0 = blockIdx.x * 128, n0 = blockIdx.y * 128;
  const int mode = blockIdx.z;
  const unsigned short* Bt = WT + (size_t)mode * 1048576;
  const int wr = w >> 1, wc = w & 1;
  const int srow = lane >> 2, scol = lane & 3;
  f32x4 acc[4][4] = {};
  for (int k0 = 0; k0 < 1024; k0 += 64) {
#pragma unroll
    for (int p = 0; p < 2; ++p)
#pragma unroll
      for (int c = 0; c < 2; ++c) {
        int chunk = w * 2 + c;
        gload16(A + (size_t)(m0 + chunk * 16 + srow) * 1024 + k0 + p * 32 + scol * 8,
                (char*)As[p] + chunk * 1024);
        gload16(Bt + (size_t)(n0 + chunk * 16 + srow) * 1024 + k0 + p * 32 + scol * 8,
                (char*)Bs[p] + chunk * 1024);
      }
    __syncthreads();
#pragma unroll
    for (int p = 0; p < 2; ++p) {
      short8 af[4], bf[4];
#pragma unroll
      for (int i = 0; i < 4; ++i) {
        af[i] = *(const short8*)((const char*)As[p] +
                ((wr * 64 + i * 16 + (lane & 15)) * 64 + (lane >> 4) * 16));
        bf[i] = *(const short8*)((const char*)Bs[p] +
                ((wc * 64 + i * 16 + (lane & 15)) * 64 + (lane >> 4) * 16));
      }
#pragma unroll
      for (int i = 0; i < 4; ++i)
#pragma unroll
        for (int j = 0; j < 4; ++j)
          acc[i][j] = __builtin_amdgcn_mfma_f32_16x16x32_bf16(af[i], bf[j], acc[i][j], 0, 0, 0);
    }
    __syncthreads();
  }

  if (mode < 2) {
    unsigned short* dst = mode ? Kb : Qb;
    const float qscale = mode ? 1.0f : 0.125f * 1.44269504088896f;
#pragma unroll
    for (int i = 0; i < 4; ++i) {
#pragma unroll
      for (int j = 0; j < 4; ++j) {
        int n = n0 + wc * 64 + j * 16 + (lane & 15);
        int h = n >> 6, d = n & 63;
        int pairIdx = d >> 1;
        bool even = (n & 1) == 0;
#pragma unroll
        for (int r = 0; r < 4; ++r) {
          int m = m0 + wr * 64 + i * 16 + (lane >> 4) * 4 + r;
          int b = m >> 11, s = m & 2047;
          float v = acc[i][j][r];
          float pv = __shfl_xor(v, 1);
          float c = ctab[s * 32 + pairIdx], sn = stab[s * 32 + pairIdx];
          float ov = (even ? (v * c - pv * sn) : (pv * sn + v * c)) * qscale;
          dst[(size_t)((h * 2 + b) * 2048 + s) * 64 + d] = f2b(ov);
        }
      }
    }
  } else {
#pragma unroll
    for (int i = 0; i < 4; ++i) {
#pragma unroll
      for (int j = 0; j < 4; ++j) {
        int n = n0 + wc * 64 + j * 16 + (lane & 15);
        int h = n >> 6, d = n & 63;
        int mBase = m0 + wr * 64 + i * 16 + (lane >> 4) * 4;
        int b = mBase >> 11, s = mBase & 2047;
        ushort4v pk = { f2b(acc[i][j][0]), f2b(acc[i][j][1]),
                        f2b(acc[i][j][2]), f2b(acc[i][j][3]) };
        *(ushort4v*)(VTb + (size_t)((h * 2 + b) * 64 + d) * 2048 + s) = pk;
      }
    }
  }
}

// ---------------- final GEMM: 64x128 tile, 2-wave blocks, fp32 out ----------------

__global__ __launch_bounds__(128) void gemm_final_kernel(
    const unsigned short* __restrict__ A, const unsigned short* __restrict__ Bt,
    float* __restrict__ Fout) {
  __shared__ unsigned short As[64 * 32];
  __shared__ unsigned short Bs[128 * 32];
  const int tid = threadIdx.x;
  const int w = tid >> 6, lane = tid & 63;
  const int m0 = blockIdx.x * 64, n0 = blockIdx.y * 128;
  const int srow = lane >> 2, scol = lane & 3;
  f32x4 acc[4][4] = {};
  for (int k0 = 0; k0 < 1024; k0 += 32) {
#pragma unroll
    for (int c = 0; c < 2; ++c) {
      int chunk = w * 2 + c;
      gload16(A + (size_t)(m0 + chunk * 16 + srow) * 1024 + k0 + scol * 8,
              (char*)As + chunk * 1024);
    }
#pragma unroll
    for (int c = 0; c < 4; ++c) {
      int chunk = w * 4 + c;
      gload16(Bt + (size_t)(n0 + chunk * 16 + srow) * 1024 + k0 + scol * 8,
              (char*)Bs + chunk * 1024);
    }
    __syncthreads();
    short8 af[4], bf[4];
#pragma unroll
    for (int i = 0; i < 4; ++i) {
      af[i] = *(const short8*)((const char*)As +
              ((i * 16 + (lane & 15)) * 64 + (lane >> 4) * 16));
      bf[i] = *(const short8*)((const char*)Bs +
              ((w * 64 + i * 16 + (lane & 15)) * 64 + (lane >> 4) * 16));
    }
#pragma unroll
    for (int i = 0; i < 4; ++i)
#pragma unroll
      for (int j = 0; j < 4; ++j)
        acc[i][j] = __builtin_amdgcn_mfma_f32_16x16x32_bf16(af[i], bf[j], acc[i][j], 0, 0, 0);
    __syncthreads();
  }
#pragma unroll
  for (int i = 0; i < 4; ++i)
#pragma unroll
    for (int j = 0; j < 4; ++j) {
      int n = n0 + w * 64 + j * 16 + (lane & 15);
#pragma unroll
      for (int r = 0; r < 4; ++r) {
        int m = m0 + i * 16 + (lane >> 4) * 4 + r;
        Fout[(size_t)m * 1024 + n] = acc[i][j][r];
      }
    }
}

// ---------------- causal flash attention ----------------
// r12 pair structure + (a) shared-fragment H/L fusion with transient frag regs
// (each K/V b128 read feeds both paths' MFMAs; r5's failure was caching kf[8] =
// +32 live VGPR -- here frags live only inside one ct step) and (b) defer-max
// (T13) + split ps partials. One Psw region, sequential P roundtrips.

__device__ __forceinline__ void softmax_defer(f32x4* s, float& m, float& ls, f32x4* o) {
  float t0 = fmaxf(fmaxf(s[0][0], s[0][1]), fmaxf(s[0][2], s[0][3]));
  float t1 = fmaxf(fmaxf(s[1][0], s[1][1]), fmaxf(s[1][2], s[1][3]));
  float t2 = fmaxf(fmaxf(s[2][0], s[2][1]), fmaxf(s[2][2], s[2][3]));
  float t3 = fmaxf(fmaxf(s[3][0], s[3][1]), fmaxf(s[3][2], s[3][3]));
  float mx = xor32max(xor16max(fmaxf(fmaxf(t0, t1), fmaxf(t2, t3))));
  if (__any(mx > m + 8.0f)) {  // defer-max: rescale only on real growth
    float nm = fmaxf(m, mx);
    float al = exp2fast(m - nm);
    m = nm;
    ls *= al;
#pragma unroll
    for (int ct = 0; ct < 4; ++ct)
#pragma unroll
      for (int r = 0; r < 4; ++r) o[ct][r] *= al;
  }
  float ps0 = 0.f, ps1 = 0.f;
#pragma unroll
  for (int ct = 0; ct < 4; ++ct)
#pragma unroll
    for (int r = 0; r < 4; ++r) {
      float p = exp2fast(s[ct][r] - m);
      s[ct][r] = p;
      if (ct < 2) ps0 += p; else ps1 += p;
    }
  ls += ps0 + ps1;
}

__device__ __forceinline__ void cmask16(f32x4* s, int rel) {
#pragma unroll
  for (int ct = 0; ct < 4; ++ct)
#pragma unroll
    for (int r = 0; r < 4; ++r)
      if (ct * 16 + r > rel) s[ct][r] = -__builtin_inff();
}

__device__ __forceinline__ void pwrite16(const f32x4* s, char* Psw, int lq, int lh) {
  const int swq = (lq & 7) << 4;
#pragma unroll
  for (int ct = 0; ct < 4; ++ct) {
    uint2v pk = { cvtpk(s[ct][0], s[ct][1]), cvtpk(s[ct][2], s[ct][3]) };
    *(uint2v*)(Psw + lq * 128 + ((ct * 32 + lh * 8) ^ swq)) = pk;
  }
}

__device__ __forceinline__ void pread16(short8* pa, const char* Psw, int lq, int lh) {
  const int swq = (lq & 7) << 4;
#pragma unroll
  for (int half = 0; half < 2; ++half)
    pa[half] = *(const short8*)(Psw + lq * 128 + ((half * 64 + lh * 16) ^ swq));
}

__device__ __forceinline__ void store_o(
    const f32x4* o, float ls, char* Psw, unsigned short* __restrict__ Ob,
    int lane, int lq, int lh, int w, int qb, int h, int b) {
  float l = xor32add(xor16add(ls));  // deferred l reduction
  float invl = 1.0f / l;
#pragma unroll
  for (int ct = 0; ct < 4; ++ct)
#pragma unroll
    for (int r = 0; r < 4; ++r) {
      int d = ct * 16 + lh * 4 + r;
      *(unsigned short*)(Psw + lq * 128 + ((2 * d) ^ ((lq & 7) << 4))) =
          f2b(o[ct][r] * invl);
    }
  __builtin_amdgcn_wave_barrier();  // Psw is wave-private
#pragma unroll
  for (int pass = 0; pass < 2; ++pass) {
    int q2 = pass * 8 + (lane >> 3), d0 = (lane & 7) * 8;
    short8 vrow = *(const short8*)(Psw + q2 * 128 + ((2 * d0) ^ ((q2 & 7) << 4)));
    int s = qb + w * 16 + q2;
    *(short8*)(Ob + ((size_t)(b * 2048 + s)) * 1024 + h * 64 + d0) = vrow;
  }
  __builtin_amdgcn_wave_barrier();
}

__global__ __launch_bounds__(256) void attn_kernel(
    const unsigned short* __restrict__ Qb, const unsigned short* __restrict__ Kb,
    const unsigned short* __restrict__ VTb, unsigned short* __restrict__ Ob) {
  __shared__ unsigned short Ks[2][64 * 64];
  __shared__ unsigned short Vs[2][64 * 64];
  __shared__ unsigned short Ps[4 * 16 * 64];
  const int tid = threadIdx.x, w = tid >> 6, lane = tid & 63;
  const int qtL = blockIdx.x, qtH = 31 - blockIdx.x;
  const int hb = blockIdx.y;
  const int h = hb >> 1, b = hb & 1;
  const unsigned short* Qhb = Qb + (size_t)hb * 2048 * 64;
  const unsigned short* Khb = Kb + (size_t)hb * 2048 * 64;
  const unsigned short* Vhb = VTb + (size_t)hb * 64 * 2048;
  char* Psw = (char*)Ps + w * 2048;
  const int lq = lane & 15, lh = lane >> 4;
  const int wq16 = w * 16;
  const int swq = (lq & 7) << 4;
  const int rel = wq16 + lq - 4 * lh;  // diag-mask threshold (tile-local)

  short8 aqL[2], aqH[2];
  {
    int rowL = qtL * 64 + wq16 + lq;
    int rowH = qtH * 64 + wq16 + lq;
#pragma unroll
    for (int half = 0; half < 2; ++half) {
      aqL[half] = *(const short8*)(Qhb + (size_t)rowL * 64 + half * 32 + lh * 8);
      aqH[half] = *(const short8*)(Qhb + (size_t)rowH * 64 + half * 32 + lh * 8);
    }
  }
  float mL = -__builtin_inff(), lsL = 0.f;
  float mH = -__builtin_inff(), lsH = 0.f;
  f32x4 oL[4] = {}, oH[4] = {};

  // staging: thread owns rows r0, r0+32 (16B each)
  const int r0 = tid >> 3, f0 = tid & 7;
  const int so0 = r0 * 128 + ((f0 * 16) ^ ((r0 & 7) << 4));
  short8 gK[2], gV[2];
  gK[0] = *(const short8*)(Khb + (size_t)r0 * 64 + f0 * 8);
  gK[1] = *(const short8*)(Khb + (size_t)(r0 + 32) * 64 + f0 * 8);
  gV[0] = *(const short8*)(Vhb + (size_t)r0 * 2048 + f0 * 8);
  gV[1] = *(const short8*)(Vhb + (size_t)(r0 + 32) * 2048 + f0 * 8);
  *(short8*)((char*)Ks[0] + so0) = gK[0];
  *(short8*)((char*)Ks[0] + so0 + 32 * 128) = gK[1];
  *(short8*)((char*)Vs[0] + so0) = gV[0];
  *(short8*)((char*)Vs[0] + so0 + 32 * 128) = gV[1];
  __syncthreads();

  for (int kt = 0; kt <= qtH; ++kt) {
    const int cur = kt & 1;
    if (kt < qtH) {  // issue next tile's loads; latency hides under compute
      int kk0 = (kt + 1) * 64;
      gK[0] = *(const short8*)(Khb + (size_t)(kk0 + r0) * 64 + f0 * 8);
      gK[1] = *(const short8*)(Khb + (size_t)(kk0 + r0 + 32) * 64 + f0 * 8);
      gV[0] = *(const short8*)(Vhb + (size_t)r0 * 2048 + kk0 + f0 * 8);
      gV[1] = *(const short8*)(Vhb + (size_t)(r0 + 32) * 2048 + kk0 + f0 * 8);
    }
    const char* Ksb = (const char*)Ks[cur];
    const char* Vsb = (const char*)Vs[cur];
    if (kt <= qtL) {
      // ---- fused H+L: each K/V frag read once, transient regs ----
      f32x4 sH[4] = {}, sL[4] = {};
      __builtin_amdgcn_s_setprio(1);
#pragma unroll
      for (int ct = 0; ct < 4; ++ct) {
        const char* base = Ksb + (ct * 16 + lq) * 128;
        short8 ak0 = *(const short8*)(base + ((lh * 16) ^ swq));
        short8 ak1 = *(const short8*)(base + ((64 + lh * 16) ^ swq));
        sH[ct] = __builtin_amdgcn_mfma_f32_16x16x32_bf16(ak0, aqH[0], sH[ct], 0, 0, 0);
        sH[ct] = __builtin_amdgcn_mfma_f32_16x16x32_bf16(ak1, aqH[1], sH[ct], 0, 0, 0);
        sL[ct] = __builtin_amdgcn_mfma_f32_16x16x32_bf16(ak0, aqL[0], sL[ct], 0, 0, 0);
        sL[ct] = __builtin_amdgcn_mfma_f32_16x16x32_bf16(ak1, aqL[1], sL[ct], 0, 0, 0);
      }
      __builtin_amdgcn_s_setprio(0);
      if (kt == qtL) cmask16(sL, rel);
      softmax_defer(sH, mH, lsH, oH);
      softmax_defer(sL, mL, lsL, oL);
      short8 paH[2], paL[2];
      pwrite16(sH, Psw, lq, lh);
      __builtin_amdgcn_wave_barrier();
      pread16(paH, Psw, lq, lh);
      __builtin_amdgcn_wave_barrier();
      pwrite16(sL, Psw, lq, lh);
      __builtin_amdgcn_wave_barrier();
      pread16(paL, Psw, lq, lh);
      __builtin_amdgcn_s_setprio(1);
#pragma unroll
      for (int ct = 0; ct < 4; ++ct) {
        const char* base = Vsb + (ct * 16 + lq) * 128;
        short8 av0 = *(const short8*)(base + ((lh * 16) ^ swq));
        short8 av1 = *(const short8*)(base + ((64 + lh * 16) ^ swq));
        oH[ct] = __builtin_amdgcn_mfma_f32_16x16x32_bf16(av0, paH[0], oH[ct], 0, 0, 0);
        oH[ct] = __builtin_amdgcn_mfma_f32_16x16x32_bf16(av1, paH[1], oH[ct], 0, 0, 0);
        oL[ct] = __builtin_amdgcn_mfma_f32_16x16x32_bf16(av0, paL[0], oL[ct], 0, 0, 0);
        oL[ct] = __builtin_amdgcn_mfma_f32_16x16x32_bf16(av1, paL[1], oL[ct], 0, 0, 0);
      }
      __builtin_amdgcn_s_setprio(0);
    } else {
      // ---- H only ----
      f32x4 sH[4] = {};
      __builtin_amdgcn_s_setprio(1);
#pragma unroll
      for (int ct = 0; ct < 4; ++ct) {
        const char* base = Ksb + (ct * 16 + lq) * 128;
        short8 ak0 = *(const short8*)(base + ((lh * 16) ^ swq));
        short8 ak1 = *(const short8*)(base + ((64 + lh * 16) ^ swq));
        sH[ct] = __builtin_amdgcn_mfma_f32_16x16x32_bf16(ak0, aqH[0], sH[ct], 0, 0, 0);
        sH[ct] = __builtin_amdgcn_mfma_f32_16x16x32_bf16(ak1, aqH[1], sH[ct], 0, 0, 0);
      }
      __builtin_amdgcn_s_setprio(0);
      if (kt == qtH) cmask16(sH, rel);
      softmax_defer(sH, mH, lsH, oH);
      short8 paH[2];
      pwrite16(sH, Psw, lq, lh);
      __builtin_amdgcn_wave_barrier();
      pread16(paH, Psw, lq, lh);
      __builtin_amdgcn_s_setprio(1);
#pragma unroll
      for (int ct = 0; ct < 4; ++ct) {
        const char* base = Vsb + (ct * 16 + lq) * 128;
        short8 av0 = *(const short8*)(base + ((lh * 16) ^ swq));
        short8 av1 = *(const short8*)(base + ((64 + lh * 16) ^ swq));
        oH[ct] = __builtin_amdgcn_mfma_f32_16x16x32_bf16(av0, paH[0], oH[ct], 0, 0, 0);
        oH[ct] = __builtin_amdgcn_mfma_f32_16x16x32_bf16(av1, paH[1], oH[ct], 0, 0, 0);
      }
      __builtin_amdgcn_s_setprio(0);
    }
    if (kt < qtH) {  // write next tile into the other buffer
      *(short8*)((char*)Ks[cur ^ 1] + so0) = gK[0];
      *(short8*)((char*)Ks[cur ^ 1] + so0 + 32 * 128) = gK[1];
      *(short8*)((char*)Vs[cur ^ 1] + so0) = gV[0];
      *(short8*)((char*)Vs[cur ^ 1] + so0 + 32 * 128) = gV[1];
    }
    __syncthreads();
  }

  store_o(oL, lsL, Psw, Ob, lane, lq, lh, w, qtL * 64, h, b);
  store_o(oH, lsH, Psw, Ob, lane, lq, lh, w, qtH * 64, h, b);
}

// ---------------- launch ----------------

extern "C" void kernel_launch(void* const* d_in, const int* in_sizes, int n_in,
                              void* d_out, int out_size, void* d_ws, size_t ws_size,
                              hipStream_t stream) {
  const float* x  = (const float*)d_in[0];
  const float* wq = (const float*)d_in[1];
  const float* wk = (const float*)d_in[2];
  const float* wv = (const float*)d_in[3];
  const float* wo = (const float*)d_in[4];
  float* out = (float*)d_out;

  char* ws = (char*)d_ws;
  const size_t SZ = 8388608;  // 8 MiB
  unsigned short* xb  = (unsigned short*)(ws);
  unsigned short* wT  = (unsigned short*)(ws + SZ);       // 4 x 2MiB (q,k,v,o)
  unsigned short* Qb  = (unsigned short*)(ws + 2 * SZ);
  unsigned short* Kb  = (unsigned short*)(ws + 3 * SZ);
  unsigned short* VTb = (unsigned short*)(ws + 4 * SZ);
  unsigned short* Ob  = (unsigned short*)(ws + 5 * SZ);
  float* ctab = (float*)(ws + 6 * SZ);
  float* stab = (float*)(ws + 6 * SZ + 262144);
  if (ws_size < 6 * SZ + 2 * 262144) return;  // ws too small: fail loudly (zeros)

  prep_kernel<<<8448, 256, 0, stream>>>(x, wq, wk, wv, wo, xb, wT, ctab, stab);
  gemm_kernel<<<dim3(32, 8, 3), 256, 0, stream>>>(xb, wT, Qb, Kb, VTb, ctab, stab);
  attn_kernel<<<dim3(16, 32), 256, 0, stream>>>(Qb, Kb, VTb, Ob);
  gemm_final_kernel<<<dim3(64, 8), 128, 0, stream>>>(Ob, wT + 3 * 1048576, out);
}

// Round 15
// 133.083 us; speedup vs baseline: 1.0566x; 1.0041x over previous
//
#include <hip/hip_runtime.h>
#include <stdint.h>

typedef __attribute__((ext_vector_type(8))) short short8;
typedef __attribute__((ext_vector_type(4))) float f32x4;
typedef __attribute__((ext_vector_type(4))) unsigned short ushort4v;
typedef __attribute__((ext_vector_type(2))) unsigned int uint2v;

static __device__ __forceinline__ unsigned short f2b(float f) {
  union { float f; unsigned int u; } v; v.f = f;
  unsigned int r = v.u + 0x7FFFu + ((v.u >> 16) & 1u);
  return (unsigned short)(r >> 16);
}

static __device__ __forceinline__ float exp2fast(float x) {
#if __has_builtin(__builtin_amdgcn_exp2f)
  return __builtin_amdgcn_exp2f(x);
#else
  return exp2f(x);
#endif
}

static __device__ __forceinline__ unsigned int cvtpk(float lo, float hi) {
  unsigned int r;
  asm("v_cvt_pk_bf16_f32 %0, %1, %2" : "=v"(r) : "v"(lo), "v"(hi));
  return r;
}

// Cross-lane ^16 / ^32 reduces via permlane*_swap (VALU) - verified r5/r6.
static __device__ __forceinline__ float xor16max(float x) {
#if __has_builtin(__builtin_amdgcn_permlane16_swap)
  unsigned u = __float_as_uint(x);
  uint2v r = __builtin_amdgcn_permlane16_swap(u, u, false, false);
  return fmaxf(__uint_as_float(r[0]), __uint_as_float(r[1]));
#else
  return fmaxf(x, __shfl_xor(x, 16));
#endif
}
static __device__ __forceinline__ float xor32max(float x) {
#if __has_builtin(__builtin_amdgcn_permlane32_swap)
  unsigned u = __float_as_uint(x);
  uint2v r = __builtin_amdgcn_permlane32_swap(u, u, false, false);
  return fmaxf(__uint_as_float(r[0]), __uint_as_float(r[1]));
#else
  return fmaxf(x, __shfl_xor(x, 32));
#endif
}
static __device__ __forceinline__ float xor16add(float x) {
#if __has_builtin(__builtin_amdgcn_permlane16_swap)
  unsigned u = __float_as_uint(x);
  uint2v r = __builtin_amdgcn_permlane16_swap(u, u, false, false);
  return __uint_as_float(r[0]) + __uint_as_float(r[1]);
#else
  return x + __shfl_xor(x, 16);
#endif
}
static __device__ __forceinline__ float xor32add(float x) {
#if __has_builtin(__builtin_amdgcn_permlane32_swap)
  unsigned u = __float_as_uint(x);
  uint2v r = __builtin_amdgcn_permlane32_swap(u, u, false, false);
  return __uint_as_float(r[0]) + __uint_as_float(r[1]);
#else
  return x + __shfl_xor(x, 32);
#endif
}

static __device__ __forceinline__ void gload16(const void* g, void* l) {
  __builtin_amdgcn_global_load_lds(
      (const __attribute__((address_space(1))) unsigned int*)g,
      (__attribute__((address_space(3))) unsigned int*)l, 16, 0, 0);
}

// ---------------- fused prep: cast_x | weight transpose | rope tables ----------------

__global__ __launch_bounds__(256) void prep_kernel(
    const float* __restrict__ x, const float* __restrict__ wq,
    const float* __restrict__ wk, const float* __restrict__ wv,
    const float* __restrict__ wo, unsigned short* __restrict__ xb,
    unsigned short* __restrict__ wT, float* __restrict__ ct,
    float* __restrict__ st) {
  __shared__ float t[32][33];
  const int bid = blockIdx.x, tid = threadIdx.x;
  if (bid < 4096) {  // cast x -> bf16
    int i = (bid * 256 + tid) * 4;
    float4 v = *(const float4*)(x + i);
    ushort4v o = { f2b(v.x), f2b(v.y), f2b(v.z), f2b(v.w) };
    *(ushort4v*)(xb + i) = o;
  } else if (bid < 8192) {  // transpose+cast weights
    int tt = bid - 4096;
    int z = tt >> 10, xy = tt & 1023;
    const float* src = (z == 0) ? wq : (z == 1) ? wk : (z == 2) ? wv : wo;
    unsigned short* dst = wT + (size_t)z * 1048576;
    int tx = tid & 31, ty = tid >> 5;
    int n0 = (xy & 31) * 32, k0 = (xy >> 5) * 32;
#pragma unroll
    for (int i = 0; i < 4; ++i) {
      int r = ty + i * 8;
      t[r][tx] = src[(size_t)(k0 + r) * 1024 + n0 + tx];
    }
    __syncthreads();
#pragma unroll
    for (int i = 0; i < 4; ++i) {
      int r = ty + i * 8;
      dst[(size_t)(n0 + r) * 1024 + k0 + tx] = f2b(t[tx][r]);
    }
  } else {  // rope tables (2048*32 entries)
    int i = (bid - 8192) * 256 + tid;
    int s = i >> 5, p = i & 31;
    float ang = (float)s * powf(10000.0f, -(float)(2 * p) / 64.0f);
    ct[i] = cosf(ang);
    st[i] = sinf(ang);
  }
}

// ---------------- QKV GEMM: 128x128 tile, K-step 64 via two BK=32 LDS panels --------

__global__ __launch_bounds__(256) void gemm_kernel(
    const unsigned short* __restrict__ A, const unsigned short* __restrict__ WT,
    unsigned short* __restrict__ Qb, unsigned short* __restrict__ Kb,
    unsigned short* __restrict__ VTb,
    const float* __restrict__ ctab, const float* __restrict__ stab) {
  __shared__ unsigned short As[2][128 * 32];
  __shared__ unsigned short Bs[2][128 * 32];
  const int tid = threadIdx.x;
  const int w = tid >> 6, lane = tid & 63;
  const int m0 = blockIdx.x * 128, n0 = blockIdx.y * 128;
  const int mode = blockIdx.z;
  const unsigned short* Bt = WT + (size_t)mode * 1048576;
  const int wr = w >> 1, wc = w & 1;
  const int srow = lane >> 2, scol = lane & 3;
  f32x4 acc[4][4] = {};
  for (int k0 = 0; k0 < 1024; k0 += 64) {
#pragma unroll
    for (int p = 0; p < 2; ++p)
#pragma unroll
      for (int c = 0; c < 2; ++c) {
        int chunk = w * 2 + c;
        gload16(A + (size_t)(m0 + chunk * 16 + srow) * 1024 + k0 + p * 32 + scol * 8,
                (char*)As[p] + chunk * 1024);
        gload16(Bt + (size_t)(n0 + chunk * 16 + srow) * 1024 + k0 + p * 32 + scol * 8,
                (char*)Bs[p] + chunk * 1024);
      }
    __syncthreads();
#pragma unroll
    for (int p = 0; p < 2; ++p) {
      short8 af[4], bf[4];
#pragma unroll
      for (int i = 0; i < 4; ++i) {
        af[i] = *(const short8*)((const char*)As[p] +
                ((wr * 64 + i * 16 + (lane & 15)) * 64 + (lane >> 4) * 16));
        bf[i] = *(const short8*)((const char*)Bs[p] +
                ((wc * 64 + i * 16 + (lane & 15)) * 64 + (lane >> 4) * 16));
      }
#pragma unroll
      for (int i = 0; i < 4; ++i)
#pragma unroll
        for (int j = 0; j < 4; ++j)
          acc[i][j] = __builtin_amdgcn_mfma_f32_16x16x32_bf16(af[i], bf[j], acc[i][j], 0, 0, 0);
    }
    __syncthreads();
  }

  if (mode < 2) {
    unsigned short* dst = mode ? Kb : Qb;
    const float qscale = mode ? 1.0f : 0.125f * 1.44269504088896f;
#pragma unroll
    for (int i = 0; i < 4; ++i) {
#pragma unroll
      for (int j = 0; j < 4; ++j) {
        int n = n0 + wc * 64 + j * 16 + (lane & 15);
        int h = n >> 6, d = n & 63;
        int pairIdx = d >> 1;
        bool even = (n & 1) == 0;
#pragma unroll
        for (int r = 0; r < 4; ++r) {
          int m = m0 + wr * 64 + i * 16 + (lane >> 4) * 4 + r;
          int b = m >> 11, s = m & 2047;
          float v = acc[i][j][r];
          float pv = __shfl_xor(v, 1);
          float c = ctab[s * 32 + pairIdx], sn = stab[s * 32 + pairIdx];
          float ov = (even ? (v * c - pv * sn) : (pv * sn + v * c)) * qscale;
          dst[(size_t)((h * 2 + b) * 2048 + s) * 64 + d] = f2b(ov);
        }
      }
    }
  } else {
#pragma unroll
    for (int i = 0; i < 4; ++i) {
#pragma unroll
      for (int j = 0; j < 4; ++j) {
        int n = n0 + wc * 64 + j * 16 + (lane & 15);
        int h = n >> 6, d = n & 63;
        int mBase = m0 + wr * 64 + i * 16 + (lane >> 4) * 4;
        int b = mBase >> 11, s = mBase & 2047;
        ushort4v pk = { f2b(acc[i][j][0]), f2b(acc[i][j][1]),
                        f2b(acc[i][j][2]), f2b(acc[i][j][3]) };
        *(ushort4v*)(VTb + (size_t)((h * 2 + b) * 64 + d) * 2048 + s) = pk;
      }
    }
  }
}

// ---------------- final GEMM: 64x128 tile, 2-wave blocks, fp32 out ----------------

__global__ __launch_bounds__(128) void gemm_final_kernel(
    const unsigned short* __restrict__ A, const unsigned short* __restrict__ Bt,
    float* __restrict__ Fout) {
  __shared__ unsigned short As[64 * 32];
  __shared__ unsigned short Bs[128 * 32];
  const int tid = threadIdx.x;
  const int w = tid >> 6, lane = tid & 63;
  const int m0 = blockIdx.x * 64, n0 = blockIdx.y * 128;
  const int srow = lane >> 2, scol = lane & 3;
  f32x4 acc[4][4] = {};
  for (int k0 = 0; k0 < 1024; k0 += 32) {
#pragma unroll
    for (int c = 0; c < 2; ++c) {
      int chunk = w * 2 + c;
      gload16(A + (size_t)(m0 + chunk * 16 + srow) * 1024 + k0 + scol * 8,
              (char*)As + chunk * 1024);
    }
#pragma unroll
    for (int c = 0; c < 4; ++c) {
      int chunk = w * 4 + c;
      gload16(Bt + (size_t)(n0 + chunk * 16 + srow) * 1024 + k0 + scol * 8,
              (char*)Bs + chunk * 1024);
    }
    __syncthreads();
    short8 af[4], bf[4];
#pragma unroll
    for (int i = 0; i < 4; ++i) {
      af[i] = *(const short8*)((const char*)As +
              ((i * 16 + (lane & 15)) * 64 + (lane >> 4) * 16));
      bf[i] = *(const short8*)((const char*)Bs +
              ((w * 64 + i * 16 + (lane & 15)) * 64 + (lane >> 4) * 16));
    }
#pragma unroll
    for (int i = 0; i < 4; ++i)
#pragma unroll
      for (int j = 0; j < 4; ++j)
        acc[i][j] = __builtin_amdgcn_mfma_f32_16x16x32_bf16(af[i], bf[j], acc[i][j], 0, 0, 0);
    __syncthreads();
  }
#pragma unroll
  for (int i = 0; i < 4; ++i)
#pragma unroll
    for (int j = 0; j < 4; ++j) {
      int n = n0 + w * 64 + j * 16 + (lane & 15);
#pragma unroll
      for (int r = 0; r < 4; ++r) {
        int m = m0 + i * 16 + (lane >> 4) * 4 + r;
        Fout[(size_t)m * 1024 + n] = acc[i][j][r];
      }
    }
}

// ---------------- causal flash attention (r12 inner loop + gload_lds staging) -------
// Staging now uses global_load_lds (async, no VGPR round-trip, no ds_writes).
// gload_lds writes LINEARLY (wave-uniform dest + lane*16); the XOR-swizzled LDS
// image is preserved by inverse-swizzling the per-lane GLOBAL source column
// (rule #21): for linear byte a, row r=a>>7, src col bytes = (a&127)^((r&7)<<4).

__device__ __forceinline__ void proc_tile(
    const short8 aq[2], const unsigned short* Ksb, const unsigned short* Vsb,
    char* Psw, int lq, int lh, int wq16, bool diag,
    float& m, float& ls, f32x4* o) {
  const int swq = (lq & 7) << 4;
  f32x4 sacc[4] = {};
  __builtin_amdgcn_s_setprio(1);
#pragma unroll
  for (int ct = 0; ct < 4; ++ct) {
    const char* base = (const char*)Ksb + (ct * 16 + lq) * 128;
#pragma unroll
    for (int half = 0; half < 2; ++half) {
      short8 ak = *(const short8*)(base + ((half * 64 + lh * 16) ^ swq));
      sacc[ct] = __builtin_amdgcn_mfma_f32_16x16x32_bf16(ak, aq[half], sacc[ct], 0, 0, 0);
    }
  }
  __builtin_amdgcn_s_setprio(0);

  if (diag) {  // mask if k_local = 16ct + 4lh + r > q_local = wq16 + lq
    int rel = wq16 + lq - 4 * lh;
#pragma unroll
    for (int ct = 0; ct < 4; ++ct)
#pragma unroll
      for (int r = 0; r < 4; ++r)
        if (ct * 16 + r > rel) sacc[ct][r] = -__builtin_inff();
  }

  float mx0 = fmaxf(fmaxf(sacc[0][0], sacc[0][1]), fmaxf(sacc[0][2], sacc[0][3]));
  float mx1 = fmaxf(fmaxf(sacc[1][0], sacc[1][1]), fmaxf(sacc[1][2], sacc[1][3]));
  float mx2 = fmaxf(fmaxf(sacc[2][0], sacc[2][1]), fmaxf(sacc[2][2], sacc[2][3]));
  float mx3 = fmaxf(fmaxf(sacc[3][0], sacc[3][1]), fmaxf(sacc[3][2], sacc[3][3]));
  float mx = fmaxf(fmaxf(mx0, mx1), fmaxf(mx2, mx3));
  mx = xor16max(mx);
  mx = xor32max(mx);
  float nm = fmaxf(m, mx);
  float al = exp2fast(m - nm);
  m = nm;
  float ps = 0.f;
#pragma unroll
  for (int ct = 0; ct < 4; ++ct)
#pragma unroll
    for (int r = 0; r < 4; ++r) {
      float p = exp2fast(sacc[ct][r] - nm);
      sacc[ct][r] = p;
      ps += p;
    }
  ls = ls * al + ps;  // per-lane partial; cross-lane reduce deferred to epilogue
#pragma unroll
  for (int ct = 0; ct < 4; ++ct)
#pragma unroll
    for (int r = 0; r < 4; ++r) o[ct][r] *= al;

  // P[q=lq][k=16ct+4lh+{0..3}] -> one b64 write per ct (4 contiguous k)
#pragma unroll
  for (int ct = 0; ct < 4; ++ct) {
    uint2v pk = { cvtpk(sacc[ct][0], sacc[ct][1]), cvtpk(sacc[ct][2], sacc[ct][3]) };
    *(uint2v*)(Psw + lq * 128 + ((ct * 32 + lh * 8) ^ swq)) = pk;
  }
  __builtin_amdgcn_wave_barrier();
  short8 pa[2];
#pragma unroll
  for (int half = 0; half < 2; ++half)
    pa[half] = *(const short8*)(Psw + lq * 128 + ((half * 64 + lh * 16) ^ swq));

  __builtin_amdgcn_s_setprio(1);
#pragma unroll
  for (int ct = 0; ct < 4; ++ct) {
    const char* base = (const char*)Vsb + (ct * 16 + lq) * 128;
#pragma unroll
    for (int half = 0; half < 2; ++half) {
      short8 av = *(const short8*)(base + ((half * 64 + lh * 16) ^ swq));
      o[ct] = __builtin_amdgcn_mfma_f32_16x16x32_bf16(av, pa[half], o[ct], 0, 0, 0);
    }
  }
  __builtin_amdgcn_s_setprio(0);
}

__device__ __forceinline__ void store_o(
    const f32x4* o, float ls, char* Psw, unsigned short* __restrict__ Ob,
    int lane, int lq, int lh, int w, int qb, int h, int b) {
  float l = xor32add(xor16add(ls));  // deferred l reduction
  float invl = 1.0f / l;
#pragma unroll
  for (int ct = 0; ct < 4; ++ct)
#pragma unroll
    for (int r = 0; r < 4; ++r) {
      int d = ct * 16 + lh * 4 + r;
      *(unsigned short*)(Psw + lq * 128 + ((2 * d) ^ ((lq & 7) << 4))) =
          f2b(o[ct][r] * invl);
    }
  __builtin_amdgcn_wave_barrier();  // Psw is wave-private
#pragma unroll
  for (int pass = 0; pass < 2; ++pass) {
    int q2 = pass * 8 + (lane >> 3), d0 = (lane & 7) * 8;
    short8 vrow = *(const short8*)(Psw + q2 * 128 + ((2 * d0) ^ ((q2 & 7) << 4)));
    int s = qb + w * 16 + q2;
    *(short8*)(Ob + ((size_t)(b * 2048 + s)) * 1024 + h * 64 + d0) = vrow;
  }
  __builtin_amdgcn_wave_barrier();
}

__global__ __launch_bounds__(256) void attn_kernel(
    const unsigned short* __restrict__ Qb, const unsigned short* __restrict__ Kb,
    const unsigned short* __restrict__ VTb, unsigned short* __restrict__ Ob) {
  __shared__ unsigned short Ks[2][64 * 64];
  __shared__ unsigned short Vs[2][64 * 64];
  __shared__ unsigned short Ps[4 * 16 * 64];
  const int tid = threadIdx.x, w = tid >> 6, lane = tid & 63;
  const int qtL = blockIdx.x, qtH = 31 - blockIdx.x;
  const int hb = blockIdx.y;
  const int h = hb >> 1, b = hb & 1;
  const unsigned short* Qhb = Qb + (size_t)hb * 2048 * 64;
  const unsigned short* Khb = Kb + (size_t)hb * 2048 * 64;
  const unsigned short* Vhb = VTb + (size_t)hb * 64 * 2048;
  char* Psw = (char*)Ps + w * 2048;
  const int lq = lane & 15, lh = lane >> 4;
  const int wq16 = w * 16;

  short8 aqL[2], aqH[2];
  {
    int rowL = qtL * 64 + wq16 + lq;
    int rowH = qtH * 64 + wq16 + lq;
#pragma unroll
    for (int half = 0; half < 2; ++half) {
      aqL[half] = *(const short8*)(Qhb + (size_t)rowL * 64 + half * 32 + lh * 8);
      aqH[half] = *(const short8*)(Qhb + (size_t)rowH * 64 + half * 32 + lh * 8);
    }
  }
  float mL = -__builtin_inff(), lsL = 0.f;
  float mH = -__builtin_inff(), lsH = 0.f;
  f32x4 oL[4] = {}, oH[4] = {};

  // gload_lds staging geometry: this wave fills linear bytes [w*1024, w*1024+1024)
  // and [4096 + w*1024, ...): HW dest = uniform base + lane*16. Inverse-swizzled
  // per-lane source columns (see header comment).
  const int a0 = w * 1024 + lane * 16;
  const int a1 = a0 + 4096;
  const int sr0 = a0 >> 7, sr1 = a1 >> 7;
  const int se0 = ((a0 & 127) ^ ((sr0 & 7) << 4)) >> 1;
  const int se1 = ((a1 & 127) ^ ((sr1 & 7) << 4)) >> 1;

#define STAGE_TILE(buf, kk0)                                                      \
  do {                                                                            \
    gload16(Khb + (size_t)((kk0) + sr0) * 64 + se0, (char*)Ks[buf] + w * 1024);   \
    gload16(Khb + (size_t)((kk0) + sr1) * 64 + se1,                               \
            (char*)Ks[buf] + 4096 + w * 1024);                                    \
    gload16(Vhb + (size_t)sr0 * 2048 + (kk0) + se0, (char*)Vs[buf] + w * 1024);   \
    gload16(Vhb + (size_t)sr1 * 2048 + (kk0) + se1,                               \
            (char*)Vs[buf] + 4096 + w * 1024);                                    \
  } while (0)

  STAGE_TILE(0, 0);
  __syncthreads();  // compiler drains vmcnt before barrier -> tile 0 ready

  for (int kt = 0; kt <= qtH; ++kt) {
    const int cur = kt & 1;
    if (kt < qtH) STAGE_TILE(cur ^ 1, (kt + 1) * 64);  // async into idle buffer
    proc_tile(aqH, Ks[cur], Vs[cur], Psw, lq, lh, wq16, kt == qtH, mH, lsH, oH);
    if (kt <= qtL)
      proc_tile(aqL, Ks[cur], Vs[cur], Psw, lq, lh, wq16, kt == qtL, mL, lsL, oL);
    __syncthreads();  // drains gloads; next iter reads cur^1
  }
#undef STAGE_TILE

  store_o(oL, lsL, Psw, Ob, lane, lq, lh, w, qtL * 64, h, b);
  store_o(oH, lsH, Psw, Ob, lane, lq, lh, w, qtH * 64, h, b);
}

// ---------------- launch ----------------

extern "C" void kernel_launch(void* const* d_in, const int* in_sizes, int n_in,
                              void* d_out, int out_size, void* d_ws, size_t ws_size,
                              hipStream_t stream) {
  const float* x  = (const float*)d_in[0];
  const float* wq = (const float*)d_in[1];
  const float* wk = (const float*)d_in[2];
  const float* wv = (const float*)d_in[3];
  const float* wo = (const float*)d_in[4];
  float* out = (float*)d_out;

  char* ws = (char*)d_ws;
  const size_t SZ = 8388608;  // 8 MiB
  unsigned short* xb  = (unsigned short*)(ws);
  unsigned short* wT  = (unsigned short*)(ws + SZ);       // 4 x 2MiB (q,k,v,o)
  unsigned short* Qb  = (unsigned short*)(ws + 2 * SZ);
  unsigned short* Kb  = (unsigned short*)(ws + 3 * SZ);
  unsigned short* VTb = (unsigned short*)(ws + 4 * SZ);
  unsigned short* Ob  = (unsigned short*)(ws + 5 * SZ);
  float* ctab = (float*)(ws + 6 * SZ);
  float* stab = (float*)(ws + 6 * SZ + 262144);
  if (ws_size < 6 * SZ + 2 * 262144) return;  // ws too small: fail loudly (zeros)

  prep_kernel<<<8448, 256, 0, stream>>>(x, wq, wk, wv, wo, xb, wT, ctab, stab);
  gemm_kernel<<<dim3(32, 8, 3), 256, 0, stream>>>(xb, wT, Qb, Kb, VTb, ctab, stab);
  attn_kernel<<<dim3(16, 32), 256, 0, stream>>>(Qb, Kb, VTb, Ob);
  gemm_final_kernel<<<dim3(64, 8), 128, 0, stream>>>(Ob, wT + 3 * 1048576, out);
}

// Round 16
// 130.789 us; speedup vs baseline: 1.0752x; 1.0175x over previous
//
#include <hip/hip_runtime.h>
#include <stdint.h>

typedef __attribute__((ext_vector_type(8))) short short8;
typedef __attribute__((ext_vector_type(4))) float f32x4;
typedef __attribute__((ext_vector_type(4))) unsigned short ushort4v;
typedef __attribute__((ext_vector_type(2))) unsigned int uint2v;

static __device__ __forceinline__ unsigned short f2b(float f) {
  union { float f; unsigned int u; } v; v.f = f;
  unsigned int r = v.u + 0x7FFFu + ((v.u >> 16) & 1u);
  return (unsigned short)(r >> 16);
}

static __device__ __forceinline__ float exp2fast(float x) {
#if __has_builtin(__builtin_amdgcn_exp2f)
  return __builtin_amdgcn_exp2f(x);
#else
  return exp2f(x);
#endif
}

static __device__ __forceinline__ unsigned int cvtpk(float lo, float hi) {
  unsigned int r;
  asm("v_cvt_pk_bf16_f32 %0, %1, %2" : "=v"(r) : "v"(lo), "v"(hi));
  return r;
}

// Cross-lane ^16 / ^32 reduces via permlane*_swap (VALU) - verified r5/r6.
static __device__ __forceinline__ float xor16max(float x) {
#if __has_builtin(__builtin_amdgcn_permlane16_swap)
  unsigned u = __float_as_uint(x);
  uint2v r = __builtin_amdgcn_permlane16_swap(u, u, false, false);
  return fmaxf(__uint_as_float(r[0]), __uint_as_float(r[1]));
#else
  return fmaxf(x, __shfl_xor(x, 16));
#endif
}
static __device__ __forceinline__ float xor32max(float x) {
#if __has_builtin(__builtin_amdgcn_permlane32_swap)
  unsigned u = __float_as_uint(x);
  uint2v r = __builtin_amdgcn_permlane32_swap(u, u, false, false);
  return fmaxf(__uint_as_float(r[0]), __uint_as_float(r[1]));
#else
  return fmaxf(x, __shfl_xor(x, 32));
#endif
}
static __device__ __forceinline__ float xor16add(float x) {
#if __has_builtin(__builtin_amdgcn_permlane16_swap)
  unsigned u = __float_as_uint(x);
  uint2v r = __builtin_amdgcn_permlane16_swap(u, u, false, false);
  return __uint_as_float(r[0]) + __uint_as_float(r[1]);
#else
  return x + __shfl_xor(x, 16);
#endif
}
static __device__ __forceinline__ float xor32add(float x) {
#if __has_builtin(__builtin_amdgcn_permlane32_swap)
  unsigned u = __float_as_uint(x);
  uint2v r = __builtin_amdgcn_permlane32_swap(u, u, false, false);
  return __uint_as_float(r[0]) + __uint_as_float(r[1]);
#else
  return x + __shfl_xor(x, 32);
#endif
}

static __device__ __forceinline__ void gload16(const void* g, void* l) {
  __builtin_amdgcn_global_load_lds(
      (const __attribute__((address_space(1))) unsigned int*)g,
      (__attribute__((address_space(3))) unsigned int*)l, 16, 0, 0);
}

// ---------------- fused prep: cast_x | weight transpose | rope tables ----------------

__global__ __launch_bounds__(256) void prep_kernel(
    const float* __restrict__ x, const float* __restrict__ wq,
    const float* __restrict__ wk, const float* __restrict__ wv,
    const float* __restrict__ wo, unsigned short* __restrict__ xb,
    unsigned short* __restrict__ wT, float* __restrict__ ct,
    float* __restrict__ st) {
  __shared__ float t[32][33];
  const int bid = blockIdx.x, tid = threadIdx.x;
  if (bid < 4096) {  // cast x -> bf16
    int i = (bid * 256 + tid) * 4;
    float4 v = *(const float4*)(x + i);
    ushort4v o = { f2b(v.x), f2b(v.y), f2b(v.z), f2b(v.w) };
    *(ushort4v*)(xb + i) = o;
  } else if (bid < 8192) {  // transpose+cast weights
    int tt = bid - 4096;
    int z = tt >> 10, xy = tt & 1023;
    const float* src = (z == 0) ? wq : (z == 1) ? wk : (z == 2) ? wv : wo;
    unsigned short* dst = wT + (size_t)z * 1048576;
    int tx = tid & 31, ty = tid >> 5;
    int n0 = (xy & 31) * 32, k0 = (xy >> 5) * 32;
#pragma unroll
    for (int i = 0; i < 4; ++i) {
      int r = ty + i * 8;
      t[r][tx] = src[(size_t)(k0 + r) * 1024 + n0 + tx];
    }
    __syncthreads();
#pragma unroll
    for (int i = 0; i < 4; ++i) {
      int r = ty + i * 8;
      dst[(size_t)(n0 + r) * 1024 + k0 + tx] = f2b(t[tx][r]);
    }
  } else {  // rope tables (2048*32 entries)
    int i = (bid - 8192) * 256 + tid;
    int s = i >> 5, p = i & 31;
    float ang = (float)s * powf(10000.0f, -(float)(2 * p) / 64.0f);
    ct[i] = cosf(ang);
    st[i] = sinf(ang);
  }
}

// ---------------- QKV GEMM: 128x128 tile, K64 two-panel, LDS slot-swizzled ----------
// [128][32]-bf16 tiles have 64B rows -> naive frag reads are 8-way bank conflicts
// (lanes 0-15 hit 2 of 8 bank-quads). Swizzle slot' = slot ^ ((row>>1)&3) spreads
// 16 rows over all 8 quads (2-way = free, m136). Both sides: staging source column
// pre-swizzled (gload_lds writes linearly), reads use lh ^ ((lq>>1)&3).

__global__ __launch_bounds__(256) void gemm_kernel(
    const unsigned short* __restrict__ A, const unsigned short* __restrict__ WT,
    unsigned short* __restrict__ Qb, unsigned short* __restrict__ Kb,
    unsigned short* __restrict__ VTb,
    const float* __restrict__ ctab, const float* __restrict__ stab) {
  __shared__ unsigned short As[2][128 * 32];
  __shared__ unsigned short Bs[2][128 * 32];
  const int tid = threadIdx.x;
  const int w = tid >> 6, lane = tid & 63;
  const int m0 = blockIdx.x * 128, n0 = blockIdx.y * 128;
  const int mode = blockIdx.z;
  const unsigned short* Bt = WT + (size_t)mode * 1048576;
  const int wr = w >> 1, wc = w & 1;
  const int srow = lane >> 2, scol = lane & 3;
  const int scolx = scol ^ ((srow >> 1) & 3);          // inverse-swizzled src slot
  const int lq = lane & 15, lh = lane >> 4;
  const int slotx = (lh ^ ((lq >> 1) & 3)) * 16;       // swizzled read slot (bytes)
  f32x4 acc[4][4] = {};
  for (int k0 = 0; k0 < 1024; k0 += 64) {
#pragma unroll
    for (int p = 0; p < 2; ++p)
#pragma unroll
      for (int c = 0; c < 2; ++c) {
        int chunk = w * 2 + c;
        gload16(A + (size_t)(m0 + chunk * 16 + srow) * 1024 + k0 + p * 32 + scolx * 8,
                (char*)As[p] + chunk * 1024);
        gload16(Bt + (size_t)(n0 + chunk * 16 + srow) * 1024 + k0 + p * 32 + scolx * 8,
                (char*)Bs[p] + chunk * 1024);
      }
    __syncthreads();
#pragma unroll
    for (int p = 0; p < 2; ++p) {
      short8 af[4], bf[4];
#pragma unroll
      for (int i = 0; i < 4; ++i) {
        af[i] = *(const short8*)((const char*)As[p] +
                ((wr * 64 + i * 16 + lq) * 64 + slotx));
        bf[i] = *(const short8*)((const char*)Bs[p] +
                ((wc * 64 + i * 16 + lq) * 64 + slotx));
      }
#pragma unroll
      for (int i = 0; i < 4; ++i)
#pragma unroll
        for (int j = 0; j < 4; ++j)
          acc[i][j] = __builtin_amdgcn_mfma_f32_16x16x32_bf16(af[i], bf[j], acc[i][j], 0, 0, 0);
    }
    __syncthreads();
  }

  if (mode < 2) {
    unsigned short* dst = mode ? Kb : Qb;
    const float qscale = mode ? 1.0f : 0.125f * 1.44269504088896f;
#pragma unroll
    for (int i = 0; i < 4; ++i) {
#pragma unroll
      for (int j = 0; j < 4; ++j) {
        int n = n0 + wc * 64 + j * 16 + (lane & 15);
        int h = n >> 6, d = n & 63;
        int pairIdx = d >> 1;
        bool even = (n & 1) == 0;
#pragma unroll
        for (int r = 0; r < 4; ++r) {
          int m = m0 + wr * 64 + i * 16 + (lane >> 4) * 4 + r;
          int b = m >> 11, s = m & 2047;
          float v = acc[i][j][r];
          float pv = __shfl_xor(v, 1);
          float c = ctab[s * 32 + pairIdx], sn = stab[s * 32 + pairIdx];
          float ov = (even ? (v * c - pv * sn) : (pv * sn + v * c)) * qscale;
          dst[(size_t)((h * 2 + b) * 2048 + s) * 64 + d] = f2b(ov);
        }
      }
    }
  } else {
#pragma unroll
    for (int i = 0; i < 4; ++i) {
#pragma unroll
      for (int j = 0; j < 4; ++j) {
        int n = n0 + wc * 64 + j * 16 + (lane & 15);
        int h = n >> 6, d = n & 63;
        int mBase = m0 + wr * 64 + i * 16 + (lane >> 4) * 4;
        int b = mBase >> 11, s = mBase & 2047;
        ushort4v pk = { f2b(acc[i][j][0]), f2b(acc[i][j][1]),
                        f2b(acc[i][j][2]), f2b(acc[i][j][3]) };
        *(ushort4v*)(VTb + (size_t)((h * 2 + b) * 64 + d) * 2048 + s) = pk;
      }
    }
  }
}

// ---------------- final GEMM: 64x128 tile, 2-wave blocks, slot-swizzled, fp32 out ----

__global__ __launch_bounds__(128) void gemm_final_kernel(
    const unsigned short* __restrict__ A, const unsigned short* __restrict__ Bt,
    float* __restrict__ Fout) {
  __shared__ unsigned short As[64 * 32];
  __shared__ unsigned short Bs[128 * 32];
  const int tid = threadIdx.x;
  const int w = tid >> 6, lane = tid & 63;
  const int m0 = blockIdx.x * 64, n0 = blockIdx.y * 128;
  const int srow = lane >> 2, scol = lane & 3;
  const int scolx = scol ^ ((srow >> 1) & 3);
  const int lq = lane & 15, lh = lane >> 4;
  const int slotx = (lh ^ ((lq >> 1) & 3)) * 16;
  f32x4 acc[4][4] = {};
  for (int k0 = 0; k0 < 1024; k0 += 32) {
#pragma unroll
    for (int c = 0; c < 2; ++c) {
      int chunk = w * 2 + c;
      gload16(A + (size_t)(m0 + chunk * 16 + srow) * 1024 + k0 + scolx * 8,
              (char*)As + chunk * 1024);
    }
#pragma unroll
    for (int c = 0; c < 4; ++c) {
      int chunk = w * 4 + c;
      gload16(Bt + (size_t)(n0 + chunk * 16 + srow) * 1024 + k0 + scolx * 8,
              (char*)Bs + chunk * 1024);
    }
    __syncthreads();
    short8 af[4], bf[4];
#pragma unroll
    for (int i = 0; i < 4; ++i) {
      af[i] = *(const short8*)((const char*)As + ((i * 16 + lq) * 64 + slotx));
      bf[i] = *(const short8*)((const char*)Bs + ((w * 64 + i * 16 + lq) * 64 + slotx));
    }
#pragma unroll
    for (int i = 0; i < 4; ++i)
#pragma unroll
      for (int j = 0; j < 4; ++j)
        acc[i][j] = __builtin_amdgcn_mfma_f32_16x16x32_bf16(af[i], bf[j], acc[i][j], 0, 0, 0);
    __syncthreads();
  }
#pragma unroll
  for (int i = 0; i < 4; ++i)
#pragma unroll
    for (int j = 0; j < 4; ++j) {
      int n = n0 + w * 64 + j * 16 + (lane & 15);
#pragma unroll
      for (int r = 0; r < 4; ++r) {
        int m = m0 + i * 16 + (lane >> 4) * 4 + r;
        Fout[(size_t)m * 1024 + n] = acc[i][j][r];
      }
    }
}

// ---------------- causal flash attention (r15-exact) ----------------

__device__ __forceinline__ void proc_tile(
    const short8 aq[2], const unsigned short* Ksb, const unsigned short* Vsb,
    char* Psw, int lq, int lh, int wq16, bool diag,
    float& m, float& ls, f32x4* o) {
  const int swq = (lq & 7) << 4;
  f32x4 sacc[4] = {};
  __builtin_amdgcn_s_setprio(1);
#pragma unroll
  for (int ct = 0; ct < 4; ++ct) {
    const char* base = (const char*)Ksb + (ct * 16 + lq) * 128;
#pragma unroll
    for (int half = 0; half < 2; ++half) {
      short8 ak = *(const short8*)(base + ((half * 64 + lh * 16) ^ swq));
      sacc[ct] = __builtin_amdgcn_mfma_f32_16x16x32_bf16(ak, aq[half], sacc[ct], 0, 0, 0);
    }
  }
  __builtin_amdgcn_s_setprio(0);

  if (diag) {  // mask if k_local = 16ct + 4lh + r > q_local = wq16 + lq
    int rel = wq16 + lq - 4 * lh;
#pragma unroll
    for (int ct = 0; ct < 4; ++ct)
#pragma unroll
      for (int r = 0; r < 4; ++r)
        if (ct * 16 + r > rel) sacc[ct][r] = -__builtin_inff();
  }

  float mx0 = fmaxf(fmaxf(sacc[0][0], sacc[0][1]), fmaxf(sacc[0][2], sacc[0][3]));
  float mx1 = fmaxf(fmaxf(sacc[1][0], sacc[1][1]), fmaxf(sacc[1][2], sacc[1][3]));
  float mx2 = fmaxf(fmaxf(sacc[2][0], sacc[2][1]), fmaxf(sacc[2][2], sacc[2][3]));
  float mx3 = fmaxf(fmaxf(sacc[3][0], sacc[3][1]), fmaxf(sacc[3][2], sacc[3][3]));
  float mx = fmaxf(fmaxf(mx0, mx1), fmaxf(mx2, mx3));
  mx = xor16max(mx);
  mx = xor32max(mx);
  float nm = fmaxf(m, mx);
  float al = exp2fast(m - nm);
  m = nm;
  float ps = 0.f;
#pragma unroll
  for (int ct = 0; ct < 4; ++ct)
#pragma unroll
    for (int r = 0; r < 4; ++r) {
      float p = exp2fast(sacc[ct][r] - nm);
      sacc[ct][r] = p;
      ps += p;
    }
  ls = ls * al + ps;  // per-lane partial; cross-lane reduce deferred to epilogue
#pragma unroll
  for (int ct = 0; ct < 4; ++ct)
#pragma unroll
    for (int r = 0; r < 4; ++r) o[ct][r] *= al;

  // P[q=lq][k=16ct+4lh+{0..3}] -> one b64 write per ct (4 contiguous k)
#pragma unroll
  for (int ct = 0; ct < 4; ++ct) {
    uint2v pk = { cvtpk(sacc[ct][0], sacc[ct][1]), cvtpk(sacc[ct][2], sacc[ct][3]) };
    *(uint2v*)(Psw + lq * 128 + ((ct * 32 + lh * 8) ^ swq)) = pk;
  }
  __builtin_amdgcn_wave_barrier();
  short8 pa[2];
#pragma unroll
  for (int half = 0; half < 2; ++half)
    pa[half] = *(const short8*)(Psw + lq * 128 + ((half * 64 + lh * 16) ^ swq));

  __builtin_amdgcn_s_setprio(1);
#pragma unroll
  for (int ct = 0; ct < 4; ++ct) {
    const char* base = (const char*)Vsb + (ct * 16 + lq) * 128;
#pragma unroll
    for (int half = 0; half < 2; ++half) {
      short8 av = *(const short8*)(base + ((half * 64 + lh * 16) ^ swq));
      o[ct] = __builtin_amdgcn_mfma_f32_16x16x32_bf16(av, pa[half], o[ct], 0, 0, 0);
    }
  }
  __builtin_amdgcn_s_setprio(0);
}

__device__ __forceinline__ void store_o(
    const f32x4* o, float ls, char* Psw, unsigned short* __restrict__ Ob,
    int lane, int lq, int lh, int w, int qb, int h, int b) {
  float l = xor32add(xor16add(ls));  // deferred l reduction
  float invl = 1.0f / l;
#pragma unroll
  for (int ct = 0; ct < 4; ++ct)
#pragma unroll
    for (int r = 0; r < 4; ++r) {
      int d = ct * 16 + lh * 4 + r;
      *(unsigned short*)(Psw + lq * 128 + ((2 * d) ^ ((lq & 7) << 4))) =
          f2b(o[ct][r] * invl);
    }
  __builtin_amdgcn_wave_barrier();  // Psw is wave-private
#pragma unroll
  for (int pass = 0; pass < 2; ++pass) {
    int q2 = pass * 8 + (lane >> 3), d0 = (lane & 7) * 8;
    short8 vrow = *(const short8*)(Psw + q2 * 128 + ((2 * d0) ^ ((q2 & 7) << 4)));
    int s = qb + w * 16 + q2;
    *(short8*)(Ob + ((size_t)(b * 2048 + s)) * 1024 + h * 64 + d0) = vrow;
  }
  __builtin_amdgcn_wave_barrier();
}

__global__ __launch_bounds__(256) void attn_kernel(
    const unsigned short* __restrict__ Qb, const unsigned short* __restrict__ Kb,
    const unsigned short* __restrict__ VTb, unsigned short* __restrict__ Ob) {
  __shared__ unsigned short Ks[2][64 * 64];
  __shared__ unsigned short Vs[2][64 * 64];
  __shared__ unsigned short Ps[4 * 16 * 64];
  const int tid = threadIdx.x, w = tid >> 6, lane = tid & 63;
  const int qtL = blockIdx.x, qtH = 31 - blockIdx.x;
  const int hb = blockIdx.y;
  const int h = hb >> 1, b = hb & 1;
  const unsigned short* Qhb = Qb + (size_t)hb * 2048 * 64;
  const unsigned short* Khb = Kb + (size_t)hb * 2048 * 64;
  const unsigned short* Vhb = VTb + (size_t)hb * 64 * 2048;
  char* Psw = (char*)Ps + w * 2048;
  const int lq = lane & 15, lh = lane >> 4;
  const int wq16 = w * 16;

  short8 aqL[2], aqH[2];
  {
    int rowL = qtL * 64 + wq16 + lq;
    int rowH = qtH * 64 + wq16 + lq;
#pragma unroll
    for (int half = 0; half < 2; ++half) {
      aqL[half] = *(const short8*)(Qhb + (size_t)rowL * 64 + half * 32 + lh * 8);
      aqH[half] = *(const short8*)(Qhb + (size_t)rowH * 64 + half * 32 + lh * 8);
    }
  }
  float mL = -__builtin_inff(), lsL = 0.f;
  float mH = -__builtin_inff(), lsH = 0.f;
  f32x4 oL[4] = {}, oH[4] = {};

  // gload_lds staging: wave fills linear bytes [w*1024, +1024) and [4096+w*1024);
  // inverse-swizzled per-lane source columns preserve the XOR-swizzled image.
  const int a0 = w * 1024 + lane * 16;
  const int a1 = a0 + 4096;
  const int sr0 = a0 >> 7, sr1 = a1 >> 7;
  const int se0 = ((a0 & 127) ^ ((sr0 & 7) << 4)) >> 1;
  const int se1 = ((a1 & 127) ^ ((sr1 & 7) << 4)) >> 1;

#define STAGE_TILE(buf, kk0)                                                      \
  do {                                                                            \
    gload16(Khb + (size_t)((kk0) + sr0) * 64 + se0, (char*)Ks[buf] + w * 1024);   \
    gload16(Khb + (size_t)((kk0) + sr1) * 64 + se1,                               \
            (char*)Ks[buf] + 4096 + w * 1024);                                    \
    gload16(Vhb + (size_t)sr0 * 2048 + (kk0) + se0, (char*)Vs[buf] + w * 1024);   \
    gload16(Vhb + (size_t)sr1 * 2048 + (kk0) + se1,                               \
            (char*)Vs[buf] + 4096 + w * 1024);                                    \
  } while (0)

  STAGE_TILE(0, 0);
  __syncthreads();  // compiler drains vmcnt before barrier -> tile 0 ready

  for (int kt = 0; kt <= qtH; ++kt) {
    const int cur = kt & 1;
    if (kt < qtH) STAGE_TILE(cur ^ 1, (kt + 1) * 64);  // async into idle buffer
    proc_tile(aqH, Ks[cur], Vs[cur], Psw, lq, lh, wq16, kt == qtH, mH, lsH, oH);
    if (kt <= qtL)
      proc_tile(aqL, Ks[cur], Vs[cur], Psw, lq, lh, wq16, kt == qtL, mL, lsL, oL);
    __syncthreads();  // drains gloads; next iter reads cur^1
  }
#undef STAGE_TILE

  store_o(oL, lsL, Psw, Ob, lane, lq, lh, w, qtL * 64, h, b);
  store_o(oH, lsH, Psw, Ob, lane, lq, lh, w, qtH * 64, h, b);
}

// ---------------- launch ----------------

extern "C" void kernel_launch(void* const* d_in, const int* in_sizes, int n_in,
                              void* d_out, int out_size, void* d_ws, size_t ws_size,
                              hipStream_t stream) {
  const float* x  = (const float*)d_in[0];
  const float* wq = (const float*)d_in[1];
  const float* wk = (const float*)d_in[2];
  const float* wv = (const float*)d_in[3];
  const float* wo = (const float*)d_in[4];
  float* out = (float*)d_out;

  char* ws = (char*)d_ws;
  const size_t SZ = 8388608;  // 8 MiB
  unsigned short* xb  = (unsigned short*)(ws);
  unsigned short* wT  = (unsigned short*)(ws + SZ);       // 4 x 2MiB (q,k,v,o)
  unsigned short* Qb  = (unsigned short*)(ws + 2 * SZ);
  unsigned short* Kb  = (unsigned short*)(ws + 3 * SZ);
  unsigned short* VTb = (unsigned short*)(ws + 4 * SZ);
  unsigned short* Ob  = (unsigned short*)(ws + 5 * SZ);
  float* ctab = (float*)(ws + 6 * SZ);
  float* stab = (float*)(ws + 6 * SZ + 262144);
  if (ws_size < 6 * SZ + 2 * 262144) return;  // ws too small: fail loudly (zeros)

  prep_kernel<<<8448, 256, 0, stream>>>(x, wq, wk, wv, wo, xb, wT, ctab, stab);
  gemm_kernel<<<dim3(32, 8, 3), 256, 0, stream>>>(xb, wT, Qb, Kb, VTb, ctab, stab);
  attn_kernel<<<dim3(16, 32), 256, 0, stream>>>(Qb, Kb, VTb, Ob);
  gemm_final_kernel<<<dim3(64, 8), 128, 0, stream>>>(Ob, wT + 3 * 1048576, out);
}